// Round 2
// baseline (1174.298 us; speedup 1.0000x reference)
//
#include <hip/hip_runtime.h>
#include <hip/hip_bf16.h>
#include <math.h>

// All float tensors are fp32 (verified: input npz ~141MB ≈ fp32 sizes; stub round's
// absmax == max|ref| with fp32 read of d_out). done is int32.

// ---------- small prep kernels ----------

// w [OC][IC][KHW] -> wt [IC][KHW][OC]  (wave-uniform weight reads in conv kernels)
__global__ void k_wconv_t(const float* __restrict__ w, float* __restrict__ wt,
                          int OC, int IC, int KHW) {
    int i = blockIdx.x * 256 + threadIdx.x;
    int total = OC * IC * KHW;
    if (i >= total) return;
    int khw = i % KHW; int t = i / KHW; int ic = t % IC; int oc = t / IC;
    wt[(ic * KHW + khw) * OC + oc] = w[i];
}

__global__ void k_init_state(const float* __restrict__ h0, const float* __restrict__ c0,
                             float* __restrict__ hf, float* __restrict__ cf) {
    int i = blockIdx.x * 256 + threadIdx.x;
    if (i < 16384) { hf[i] = h0[i]; cf[i] = c0[i]; }
}

__global__ void k_states_out(const float* __restrict__ hf, const float* __restrict__ cf,
                             float* __restrict__ oh, float* __restrict__ oc) {
    int i = blockIdx.x * 256 + threadIdx.x;
    if (i < 16384) { oh[i] = hf[i]; oc[i] = cf[i]; }
}

// Whh [2048][512] -> WhhT [512][2048], 32x32 LDS tiles
__global__ void k_transpose_whh(const float* __restrict__ in, float* __restrict__ out) {
    __shared__ float t[32][33];
    int bx = blockIdx.x & 15;        // k-tile (512/32)
    int by = blockIdx.x >> 4;        // j-tile (2048/32)
    int tid = threadIdx.x;
    int r = tid >> 5, c = tid & 31;  // 8 x 32
#pragma unroll
    for (int i = 0; i < 4; ++i)
        t[r + i * 8][c] = in[(by * 32 + r + i * 8) * 512 + bx * 32 + c];
    __syncthreads();
#pragma unroll
    for (int i = 0; i < 4; ++i)
        out[(bx * 32 + r + i * 8) * 2048 + by * 32 + c] = t[c][r + i * 8];
}

// ---------- convs: one thread = one (n,oh,ow), acc over all OC in regs ----------

__global__ void k_conv1(const float* __restrict__ x, const float* __restrict__ wt,
                        const float* __restrict__ bias, float* __restrict__ y) {
    int idx = blockIdx.x * 256 + threadIdx.x;            // 512*29*39 = 579072
    if (idx >= 512 * 29 * 39) return;
    int ow = idx % 39; int t = idx / 39; int oh = t % 29; int n = t / 29;
    float acc[32];
#pragma unroll
    for (int o = 0; o < 32; ++o) acc[o] = 0.f;
    const float* xb = x + ((size_t)n * 3 * 120 + oh * 4) * 160 + ow * 4;
    for (int ic = 0; ic < 3; ++ic) {
#pragma unroll
        for (int kh = 0; kh < 8; ++kh) {
            const float* xr = xb + (ic * 120 + kh) * 160;
            float xv[8];
#pragma unroll
            for (int q = 0; q < 8; ++q) xv[q] = xr[q];
            const float* wrow = wt + ((ic * 8 + kh) * 8) * 32;
#pragma unroll
            for (int kw = 0; kw < 8; ++kw) {
                float xs = xv[kw];
                const float* wp = wrow + kw * 32;
#pragma unroll
                for (int o = 0; o < 32; ++o) acc[o] += xs * wp[o];
            }
        }
    }
    float* yb = y + (size_t)n * 32 * 1131 + oh * 39 + ow;   // [n][oc][29][39]
#pragma unroll
    for (int o = 0; o < 32; ++o)
        yb[o * 1131] = fmaxf(acc[o] + bias[o], 0.f);
}

__global__ void k_conv2(const float* __restrict__ a1, const float* __restrict__ wt,
                        const float* __restrict__ bias, float* __restrict__ y) {
    int idx = blockIdx.x * 256 + threadIdx.x;            // 512*13*18 = 119808
    if (idx >= 512 * 13 * 18) return;
    int ow = idx % 18; int t = idx / 18; int oh = t % 13; int n = t / 13;
    float acc[64];
#pragma unroll
    for (int o = 0; o < 64; ++o) acc[o] = 0.f;
    const float* xb = a1 + ((size_t)n * 32 * 29 + oh * 2) * 39 + ow * 2;
    for (int ic = 0; ic < 32; ++ic) {
#pragma unroll
        for (int kh = 0; kh < 4; ++kh) {
            const float* xr = xb + (ic * 29 + kh) * 39;
            float xv[4];
#pragma unroll
            for (int q = 0; q < 4; ++q) xv[q] = xr[q];
            const float* wrow = wt + ((ic * 4 + kh) * 4) * 64;
#pragma unroll
            for (int kw = 0; kw < 4; ++kw) {
                float xs = xv[kw];
                const float* wp = wrow + kw * 64;
#pragma unroll
                for (int o = 0; o < 64; ++o) acc[o] += xs * wp[o];
            }
        }
    }
    float* yb = y + (size_t)n * 64 * 234 + oh * 18 + ow;    // [n][oc][13][18]
#pragma unroll
    for (int o = 0; o < 64; ++o)
        yb[o * 234] = fmaxf(acc[o] + bias[o], 0.f);
}

__global__ void k_conv3(const float* __restrict__ a2, const float* __restrict__ wt,
                        const float* __restrict__ bias, float* __restrict__ y) {
    int idx = blockIdx.x * 256 + threadIdx.x;            // 512*11*16 = 90112
    if (idx >= 512 * 11 * 16) return;
    int ow = idx % 16; int t = idx / 16; int oh = t % 11; int n = t / 11;
    float acc[64];
#pragma unroll
    for (int o = 0; o < 64; ++o) acc[o] = 0.f;
    const float* xb = a2 + ((size_t)n * 64 * 13 + oh) * 18 + ow;
    for (int ic = 0; ic < 64; ++ic) {
#pragma unroll
        for (int kh = 0; kh < 3; ++kh) {
            const float* xr = xb + (ic * 13 + kh) * 18;
            float xv[3];
#pragma unroll
            for (int q = 0; q < 3; ++q) xv[q] = xr[q];
            const float* wrow = wt + ((ic * 3 + kh) * 3) * 64;
#pragma unroll
            for (int kw = 0; kw < 3; ++kw) {
                float xs = xv[kw];
                const float* wp = wrow + kw * 64;
#pragma unroll
                for (int o = 0; o < 64; ++o) acc[o] += xs * wp[o];
            }
        }
    }
    // directly into flattened a3 [n][oc*176 + oh*16 + ow]
    float* yb = y + (size_t)n * 11264 + oh * 16 + ow;
#pragma unroll
    for (int o = 0; o < 64; ++o)
        yb[o * 176] = fmaxf(acc[o] + bias[o], 0.f);
}

// ---------- generic GEMM: C[M,N] = leaky(A[M,K] @ W[N,K]^T + bias, slope) ----------
// 32x32 tile, 256 threads, 2x2 per thread, k-major LDS with float2 reads.

__global__ void k_gemm(const float* __restrict__ A, const float* __restrict__ W,
                       const float* __restrict__ bias, float* __restrict__ C,
                       int M, int N, int K, float slope) {
    __shared__ float As[32][34];   // [kk][m]
    __shared__ float Ws[32][34];   // [kk][n]
    const int tid = threadIdx.x;
    const int m0 = blockIdx.y * 32, n0 = blockIdx.x * 32;
    const int ty = tid >> 4, tx = tid & 15;
    const int lr = tid >> 3, lc = (tid & 7) * 4;
    float acc00 = 0.f, acc01 = 0.f, acc10 = 0.f, acc11 = 0.f;
    for (int k0 = 0; k0 < K; k0 += 32) {
        float4 av = *(const float4*)(A + (size_t)(m0 + lr) * K + k0 + lc);
        float4 wv = {0.f, 0.f, 0.f, 0.f};
        if (n0 + lr < N) wv = *(const float4*)(W + (size_t)(n0 + lr) * K + k0 + lc);
        As[lc + 0][lr] = av.x; As[lc + 1][lr] = av.y;
        As[lc + 2][lr] = av.z; As[lc + 3][lr] = av.w;
        Ws[lc + 0][lr] = wv.x; Ws[lc + 1][lr] = wv.y;
        Ws[lc + 2][lr] = wv.z; Ws[lc + 3][lr] = wv.w;
        __syncthreads();
#pragma unroll
        for (int kk = 0; kk < 32; ++kk) {
            float2 a2 = *(const float2*)&As[kk][ty * 2];
            float2 b2 = *(const float2*)&Ws[kk][tx * 2];
            acc00 += a2.x * b2.x; acc01 += a2.x * b2.y;
            acc10 += a2.y * b2.x; acc11 += a2.y * b2.y;
        }
        __syncthreads();
    }
    const int gm = m0 + ty * 2, gn = n0 + tx * 2;
    float accs[2][2] = {{acc00, acc01}, {acc10, acc11}};
#pragma unroll
    for (int i = 0; i < 2; ++i) {
#pragma unroll
        for (int j = 0; j < 2; ++j) {
            if (gn + j < N) {
                float v = accs[i][j] + bias[gn + j];
                v = (v >= 0.f) ? v : v * slope;
                C[(size_t)(gm + i) * N + gn + j] = v;
            }
        }
    }
}

// ---------- LSTM step ----------
// grid 256 = (b:32) x (hc:8), 128 threads: gate = tid>>5, pair of h-cols.
__global__ void k_lstm_step(const float* __restrict__ P, const float* __restrict__ WhhT,
                            const float* __restrict__ bhh, const int* __restrict__ done,
                            const float* __restrict__ h_in, float* __restrict__ h_out,
                            float* __restrict__ c, float* __restrict__ nh, int t) {
    int b  = blockIdx.x >> 3;
    int hc = blockIdx.x & 7;
    int tid = threadIdx.x;                 // 128
    __shared__ float hs[512];
    __shared__ float gs[4][64];
    float m = 1.0f - (float)done[t * 32 + b];
    for (int i = tid; i < 512; i += 128) hs[i] = h_in[b * 512 + i] * m;
    __syncthreads();
    int gate = tid >> 5;                   // 0..3
    int hp = (tid & 31) * 2;               // 0,2,..,62
    int j0 = gate * 512 + hc * 64 + hp;    // even
    float acc0 = bhh[j0], acc1 = bhh[j0 + 1];
#pragma unroll 4
    for (int k = 0; k < 512; k += 4) {
        float4 h4 = *(const float4*)(&hs[k]);
        const float* hv = (const float*)&h4;
#pragma unroll
        for (int q = 0; q < 4; ++q) {
            float2 w2 = *(const float2*)(WhhT + (size_t)(k + q) * 2048 + j0);
            acc0 += hv[q] * w2.x;
            acc1 += hv[q] * w2.y;
        }
    }
    int row = t * 32 + b;
    acc0 += P[(size_t)row * 2048 + j0];
    acc1 += P[(size_t)row * 2048 + j0 + 1];
    gs[gate][hp] = acc0;
    gs[gate][hp + 1] = acc1;
    __syncthreads();
    if (tid < 64) {
        int hi = hc * 64 + tid;
        float ig = 1.f / (1.f + expf(-gs[0][tid]));
        float fg = 1.f / (1.f + expf(-gs[1][tid]));
        float gg = tanhf(gs[2][tid]);
        float og = 1.f / (1.f + expf(-gs[3][tid]));
        float cnew = fg * (c[b * 512 + hi] * m) + ig * gg;
        float hnew = og * tanhf(cnew);
        c[b * 512 + hi] = cnew;
        h_out[b * 512 + hi] = hnew;
        nh[(size_t)row * 512 + hi] = hnew;
    }
}

// ---------- launch ----------

extern "C" void kernel_launch(void* const* d_in, const int* in_sizes, int n_in,
                              void* d_out, int out_size, void* d_ws, size_t ws_size,
                              hipStream_t stream) {
    (void)in_sizes; (void)n_in; (void)out_size; (void)ws_size;
    const float* x    = (const float*)d_in[0];
    const int*   done = (const int*)  d_in[1];
    const float* h0   = (const float*)d_in[2];
    const float* c0   = (const float*)d_in[3];
    const float* w1   = (const float*)d_in[4];
    const float* b1   = (const float*)d_in[5];
    const float* w2   = (const float*)d_in[6];
    const float* b2   = (const float*)d_in[7];
    const float* w3   = (const float*)d_in[8];
    const float* b3   = (const float*)d_in[9];
    const float* fcW  = (const float*)d_in[10];
    const float* fcb  = (const float*)d_in[11];
    const float* Wih  = (const float*)d_in[12];
    const float* Whh  = (const float*)d_in[13];
    const float* bih  = (const float*)d_in[14];
    const float* bhh  = (const float*)d_in[15];
    const float* A1   = (const float*)d_in[16];
    const float* Ab1  = (const float*)d_in[17];
    const float* A2   = (const float*)d_in[18];
    const float* Ab2  = (const float*)d_in[19];
    const float* C1   = (const float*)d_in[20];
    const float* Cb1  = (const float*)d_in[21];
    const float* C2   = (const float*)d_in[22];
    const float* Cb2  = (const float*)d_in[23];
    float* out = (float*)d_out;

    char* wsp = (char*)d_ws;
    auto alloc = [&](size_t bytes) {
        char* p = wsp; wsp += (bytes + 255) & ~(size_t)255; return p;
    };
    // region0: a1 [512][32][29][39] f32 (74.12 MB); a3 [512][11264] f32 (23.07 MB)
    // aliases it (a1 dead once conv2 completes, a3 written by conv3 which reads a2).
    char*  region0 = alloc(18530304ull * 4);
    float* a1   = (float*)region0;
    float* a3   = (float*)region0;
    float* a2   = (float*)alloc(7667712ull  * 4);  // [512][64][13][18]
    float* hfc  = (float*)alloc(262144ull   * 4);  // [512][512]
    float* P    = (float*)alloc(1048576ull  * 4);  // [512][2048] = x@Wih.T + bih
    float* WhhT = (float*)alloc(1048576ull  * 4);  // [512][2048]
    float* hA   = (float*)alloc(16384ull    * 4);
    float* hB   = (float*)alloc(16384ull    * 4);
    float* cS   = (float*)alloc(16384ull    * 4);
    float* nh   = (float*)alloc(262144ull   * 4);  // [512][512]
    float* aA   = (float*)alloc(262144ull   * 4);
    float* aC   = (float*)alloc(262144ull   * 4);
    float* w1t  = (float*)alloc(6144ull  * 4);
    float* w2t  = (float*)alloc(32768ull * 4);
    float* w3t  = (float*)alloc(36864ull * 4);

    k_wconv_t<<<24, 256, 0, stream>>>(w1, w1t, 32, 3, 64);
    k_wconv_t<<<128, 256, 0, stream>>>(w2, w2t, 64, 32, 16);
    k_wconv_t<<<144, 256, 0, stream>>>(w3, w3t, 64, 64, 9);
    k_init_state<<<64, 256, 0, stream>>>(h0, c0, hA, cS);
    k_transpose_whh<<<1024, 256, 0, stream>>>(Whh, WhhT);

    k_conv1<<<2262, 256, 0, stream>>>(x, w1t, b1, a1);
    k_conv2<<<468, 256, 0, stream>>>(a1, w2t, b2, a2);
    k_conv3<<<352, 256, 0, stream>>>(a2, w3t, b3, a3);

    k_gemm<<<dim3(16, 16), 256, 0, stream>>>(a3, fcW, fcb, hfc, 512, 512, 11264, 0.2f);
    k_gemm<<<dim3(64, 16), 256, 0, stream>>>(hfc, Wih, bih, P, 512, 2048, 512, 1.0f);

    for (int t = 0; t < 16; ++t) {
        const float* hin = (t & 1) ? hB : hA;
        float* hout      = (t & 1) ? hA : hB;
        k_lstm_step<<<256, 128, 0, stream>>>(P, WhhT, bhh, done, hin, hout, cS, nh, t);
    }

    k_gemm<<<dim3(16, 16), 256, 0, stream>>>(nh, A1, Ab1, aA, 512, 512, 512, 0.01f);
    k_gemm<<<dim3(1, 16), 256, 0, stream>>>(aA, A2, Ab2, out, 512, 8, 512, 1.0f);
    k_gemm<<<dim3(16, 16), 256, 0, stream>>>(nh, C1, Cb1, aC, 512, 512, 512, 0.01f);
    k_gemm<<<dim3(1, 16), 256, 0, stream>>>(aC, C2, Cb2, out + 4096, 512, 1, 512, 1.0f);

    k_states_out<<<64, 256, 0, stream>>>(hA, cS, out + 4608, out + 20992);
}

// Round 3
// 610.959 us; speedup vs baseline: 1.9221x; 1.9221x over previous
//
#include <hip/hip_runtime.h>
#include <hip/hip_bf16.h>
#include <math.h>

typedef float f32;
using short8 = __attribute__((ext_vector_type(8))) short;   // 8 bf16 (4 VGPR)
using f32x4  = __attribute__((ext_vector_type(4))) float;   // MFMA acc

#define MFMA16(a, b, c) __builtin_amdgcn_mfma_f32_16x16x32_bf16(a, b, c, 0, 0, 0)

__device__ __forceinline__ short f2bs(float f) {
    __hip_bfloat16 h = __float2bfloat16(f);          // RNE
    return __builtin_bit_cast(short, h);
}
__device__ __forceinline__ float bs2f(short s) {
    return __uint_as_float(((unsigned)(unsigned short)s) << 16);
}

// ---------------- prep kernels ----------------

// flat fp32 -> bf16(short), n multiple of 4
__global__ void k_cvt(const float* __restrict__ in, short* __restrict__ out, int n4) {
    int i = blockIdx.x * 256 + threadIdx.x;
    if (i >= n4) return;
    float4 v = *(const float4*)(in + i * 4);
    out[i * 4 + 0] = f2bs(v.x); out[i * 4 + 1] = f2bs(v.y);
    out[i * 4 + 2] = f2bs(v.z); out[i * 4 + 3] = f2bs(v.w);
}

// w2 [64][32][4][4] -> Wc2 [oc][kh*128 + kw*32 + ic]
__global__ void k_prep_wc2(const float* __restrict__ w, short* __restrict__ o) {
    int i = blockIdx.x * 256 + threadIdx.x;
    if (i >= 32768) return;
    int oc = i >> 9, col = i & 511;
    int kh = col >> 7, kw = (col >> 5) & 3, ic = col & 31;
    o[i] = f2bs(w[((oc * 32 + ic) * 4 + kh) * 4 + kw]);
}

// w3 [64][64][3][3] -> Wc3 [oc][kh*192 + kw*64 + ic]
__global__ void k_prep_wc3(const float* __restrict__ w, short* __restrict__ o) {
    int i = blockIdx.x * 256 + threadIdx.x;
    if (i >= 36864) return;
    int oc = i / 576, col = i % 576;
    int kh = col / 192, r = col % 192, kw = r >> 6, ic = r & 63;
    o[i] = f2bs(w[((oc * 64 + ic) * 3 + kh) * 3 + kw]);
}

// fcW [512][11264] (K-order oc*176+pix) -> fcWr [512][pix*64+oc] bf16
__global__ void k_prep_fcw(const float* __restrict__ w, short* __restrict__ o) {
    int i = blockIdx.x * 256 + threadIdx.x;
    if (i >= 5767168) return;
    int row = i / 11264, col = i % 11264;
    int pix = col >> 6, oc = col & 63;
    o[i] = f2bs(w[(size_t)row * 11264 + oc * 176 + pix]);
}

__global__ void k_init_state(const float* __restrict__ h0, const float* __restrict__ c0,
                             float* __restrict__ hf, float* __restrict__ cf) {
    int i = blockIdx.x * 256 + threadIdx.x;
    if (i < 16384) { hf[i] = h0[i]; cf[i] = c0[i]; }
}

__global__ void k_states_out(const float* __restrict__ hf, const float* __restrict__ cf,
                             float* __restrict__ oh, float* __restrict__ oc) {
    int i = blockIdx.x * 256 + threadIdx.x;
    if (i < 16384) { oh[i] = hf[i]; oc[i] = cf[i]; }
}

// Whh [2048][512] -> WhhT [512][2048] fp32
__global__ void k_transpose_whh(const float* __restrict__ in, float* __restrict__ out) {
    __shared__ float t[32][33];
    int bx = blockIdx.x & 15, by = blockIdx.x >> 4;
    int tid = threadIdx.x, r = tid >> 5, c = tid & 31;
#pragma unroll
    for (int i = 0; i < 4; ++i)
        t[r + i * 8][c] = in[(by * 32 + r + i * 8) * 512 + bx * 32 + c];
    __syncthreads();
#pragma unroll
    for (int i = 0; i < 4; ++i)
        out[(bx * 32 + r + i * 8) * 2048 + by * 32 + c] = t[c][r + i * 8];
}

// ---------------- conv1 MFMA: x[512][3][120][160] f32 -> a1 NHWC [512*29*39][32] bf16 ----------------
// M=579072 (NT=36192 m-tiles), N=32, K=192 (k = ic*64 + kh*8 + kw)
__global__ void k_conv1_mfma(const float* __restrict__ x, const short* __restrict__ Wc,
                             const float* __restrict__ bias, short* __restrict__ y) {
    __shared__ short wl[32 * 200];                    // [32][192+8]
    const int tid = threadIdx.x;
    for (int i = tid; i < 768; i += 256) {            // 32 rows * 24 chunks
        int row = i / 24, cc = i % 24;
        *(short8*)&wl[row * 200 + cc * 8] = *(const short8*)&Wc[row * 192 + cc * 8];
    }
    __syncthreads();
    const int w = tid >> 6, l = tid & 63;
    const int lr = l & 15, lg = l >> 4;
    const float bc0 = bias[lr], bc1 = bias[16 + lr];
    const int gw = blockIdx.x * 4 + w, step = gridDim.x * 4 * 4;
    for (int t0 = gw * 4; t0 < 36192; t0 += step) {
        const float* abase[4]; int ok[4];
        f32x4 acc[4][2] = {};
#pragma unroll
        for (int mi = 0; mi < 4; ++mi) {
            ok[mi] = (t0 + mi) < 36192;
            unsigned m = ok[mi] ? (unsigned)((t0 + mi) * 16 + lr) : 0u;
            unsigned n = m / 1131u, pix = m % 1131u;
            unsigned oh = pix / 39u, ow = pix % 39u;
            abase[mi] = x + (size_t)n * 57600 + (oh * 4) * 160 + ow * 4;
        }
#pragma unroll
        for (int ks = 0; ks < 6; ++ks) {
            int kidx = ks * 32 + lg * 8;
            int ic = kidx >> 6, kh = (kidx & 63) >> 3;
            int off = ic * 19200 + kh * 160;
            short8 b0 = *(const short8*)&wl[lr * 200 + kidx];
            short8 b1 = *(const short8*)&wl[(16 + lr) * 200 + kidx];
#pragma unroll
            for (int mi = 0; mi < 4; ++mi) {
                const float* ap = abase[mi] + off;
                float4 f0 = *(const float4*)ap;
                float4 f1 = *(const float4*)(ap + 4);
                short8 a;
                a[0] = f2bs(f0.x); a[1] = f2bs(f0.y); a[2] = f2bs(f0.z); a[3] = f2bs(f0.w);
                a[4] = f2bs(f1.x); a[5] = f2bs(f1.y); a[6] = f2bs(f1.z); a[7] = f2bs(f1.w);
                acc[mi][0] = MFMA16(a, b0, acc[mi][0]);
                acc[mi][1] = MFMA16(a, b1, acc[mi][1]);
            }
        }
#pragma unroll
        for (int mi = 0; mi < 4; ++mi) {
            if (!ok[mi]) continue;
#pragma unroll
            for (int j = 0; j < 4; ++j) {
                size_t row = (size_t)(t0 + mi) * 16 + lg * 4 + j;
                float v0 = fmaxf(acc[mi][0][j] + bc0, 0.f);
                float v1 = fmaxf(acc[mi][1][j] + bc1, 0.f);
                y[row * 32 + lr] = f2bs(v0);
                y[row * 32 + 16 + lr] = f2bs(v1);
            }
        }
    }
}

// ---------------- conv2 MFMA: a1 NHWC -> a2 NHWC [512*13*18][64] ----------------
// M=119808 (NT=7488), N=64, K=512 (k = kh*128 + kw*32 + ic)
__global__ void k_conv2_mfma(const short* __restrict__ a1, const short* __restrict__ Wc,
                             const float* __restrict__ bias, short* __restrict__ y) {
    __shared__ short wl[64 * 520];                    // [64][512+8]
    const int tid = threadIdx.x;
    for (int i = tid; i < 4096; i += 256) {           // 64 rows * 64 chunks
        int row = i >> 6, cc = i & 63;
        *(short8*)&wl[row * 520 + cc * 8] = *(const short8*)&Wc[row * 512 + cc * 8];
    }
    __syncthreads();
    const int w = tid >> 6, l = tid & 63;
    const int lr = l & 15, lg = l >> 4;
    float bc[4];
#pragma unroll
    for (int nf = 0; nf < 4; ++nf) bc[nf] = bias[nf * 16 + lr];
    const int gw = blockIdx.x * 4 + w, step = gridDim.x * 4 * 2;
    for (int t0 = gw * 2; t0 < 7488; t0 += step) {
        const short* abase[2]; int ok[2];
        f32x4 acc[2][4] = {};
#pragma unroll
        for (int mi = 0; mi < 2; ++mi) {
            ok[mi] = (t0 + mi) < 7488;
            unsigned m = ok[mi] ? (unsigned)((t0 + mi) * 16 + lr) : 0u;
            unsigned n = m / 234u, pix = m % 234u;
            unsigned oh = pix / 18u, ow = pix % 18u;
            abase[mi] = a1 + ((size_t)(n * 29 + oh * 2) * 39 + ow * 2) * 32;
        }
#pragma unroll
        for (int ks = 0; ks < 16; ++ks) {
            int kidx = ks * 32 + lg * 8;
            int kh = kidx >> 7, kw = (kidx >> 5) & 3, ic0 = kidx & 31;
            int off = (kh * 39 + kw) * 32 + ic0;
            short8 a[2];
#pragma unroll
            for (int mi = 0; mi < 2; ++mi) a[mi] = *(const short8*)(abase[mi] + off);
#pragma unroll
            for (int nf = 0; nf < 4; ++nf) {
                short8 b = *(const short8*)&wl[(nf * 16 + lr) * 520 + kidx];
                acc[0][nf] = MFMA16(a[0], b, acc[0][nf]);
                acc[1][nf] = MFMA16(a[1], b, acc[1][nf]);
            }
        }
#pragma unroll
        for (int mi = 0; mi < 2; ++mi) {
            if (!ok[mi]) continue;
#pragma unroll
            for (int j = 0; j < 4; ++j) {
                size_t row = (size_t)(t0 + mi) * 16 + lg * 4 + j;
#pragma unroll
                for (int nf = 0; nf < 4; ++nf) {
                    float v = fmaxf(acc[mi][nf][j] + bc[nf], 0.f);
                    y[row * 64 + nf * 16 + lr] = f2bs(v);
                }
            }
        }
    }
}

// ---------------- conv3 MFMA: a2 NHWC -> a3 [512*11*16][64] bf16 (NHWC, fcWr matches) ----------------
// M=90112 (NT=5632), N=64, K=576 (k = kh*192 + kw*64 + ic)
__global__ void k_conv3_mfma(const short* __restrict__ a2, const short* __restrict__ Wc,
                             const float* __restrict__ bias, short* __restrict__ y) {
    __shared__ short wl[64 * 584];                    // [64][576+8]
    const int tid = threadIdx.x;
    for (int i = tid; i < 4608; i += 256) {           // 64 rows * 72 chunks
        int row = i / 72, cc = i % 72;
        *(short8*)&wl[row * 584 + cc * 8] = *(const short8*)&Wc[row * 576 + cc * 8];
    }
    __syncthreads();
    const int w = tid >> 6, l = tid & 63;
    const int lr = l & 15, lg = l >> 4;
    float bc[4];
#pragma unroll
    for (int nf = 0; nf < 4; ++nf) bc[nf] = bias[nf * 16 + lr];
    const int gw = blockIdx.x * 4 + w, step = gridDim.x * 4 * 2;
    for (int t0 = gw * 2; t0 < 5632; t0 += step) {
        const short* abase[2]; int ok[2];
        f32x4 acc[2][4] = {};
#pragma unroll
        for (int mi = 0; mi < 2; ++mi) {
            ok[mi] = (t0 + mi) < 5632;
            unsigned m = ok[mi] ? (unsigned)((t0 + mi) * 16 + lr) : 0u;
            unsigned n = m / 176u, pix = m % 176u;
            unsigned oh = pix >> 4, ow = pix & 15u;
            abase[mi] = a2 + ((size_t)(n * 13 + oh) * 18 + ow) * 64;
        }
#pragma unroll
        for (int ks = 0; ks < 18; ++ks) {
            int kidx = ks * 32 + lg * 8;
            int kh = kidx / 192, r = kidx % 192, kw = r >> 6, ic0 = r & 63;
            int off = (kh * 18 + kw) * 64 + ic0;
            short8 a[2];
#pragma unroll
            for (int mi = 0; mi < 2; ++mi) a[mi] = *(const short8*)(abase[mi] + off);
#pragma unroll
            for (int nf = 0; nf < 4; ++nf) {
                short8 b = *(const short8*)&wl[(nf * 16 + lr) * 584 + kidx];
                acc[0][nf] = MFMA16(a[0], b, acc[0][nf]);
                acc[1][nf] = MFMA16(a[1], b, acc[1][nf]);
            }
        }
#pragma unroll
        for (int mi = 0; mi < 2; ++mi) {
            if (!ok[mi]) continue;
#pragma unroll
            for (int j = 0; j < 4; ++j) {
                size_t row = (size_t)(t0 + mi) * 16 + lg * 4 + j;
#pragma unroll
                for (int nf = 0; nf < 4; ++nf) {
                    float v = fmaxf(acc[mi][nf][j] + bc[nf], 0.f);
                    y[row * 64 + nf * 16 + lr] = f2bs(v);
                }
            }
        }
    }
}

// ---------------- MFMA GEMM core: part[z][M][N] += A[M,K_range] @ W[N,K_range]^T ----------------
// grid (N/64, M/64, S); 256 thr = 4 waves (2x2 of 32x32)
__global__ void k_gemm_mfma(const short* __restrict__ A, const short* __restrict__ W,
                            float* __restrict__ part, int M, int N, int K, int kPerSplit) {
    __shared__ short As[64 * 40];
    __shared__ short Ws[64 * 40];
    const int tid = threadIdx.x;
    const int m0 = blockIdx.y * 64, n0 = blockIdx.x * 64;
    const int k0s = blockIdx.z * kPerSplit, k0e = k0s + kPerSplit;
    const int w = tid >> 6, l = tid & 63;
    const int wr = w >> 1, wc = w & 1;
    const int sr = tid >> 2, sc = tid & 3;
    const int lr = l & 15, lg = l >> 4;
    f32x4 acc[2][2] = {};
    for (int k0 = k0s; k0 < k0e; k0 += 32) {
        short8 av = *(const short8*)(A + (size_t)(m0 + sr) * K + k0 + sc * 8);
        short8 wv = *(const short8*)(W + (size_t)(n0 + sr) * K + k0 + sc * 8);
        __syncthreads();
        *(short8*)&As[sr * 40 + sc * 8] = av;
        *(short8*)&Ws[sr * 40 + sc * 8] = wv;
        __syncthreads();
        int cb = lg * 8;
        short8 a0 = *(const short8*)&As[(wr * 32 + lr) * 40 + cb];
        short8 a1 = *(const short8*)&As[(wr * 32 + 16 + lr) * 40 + cb];
        short8 b0 = *(const short8*)&Ws[(wc * 32 + lr) * 40 + cb];
        short8 b1 = *(const short8*)&Ws[(wc * 32 + 16 + lr) * 40 + cb];
        acc[0][0] = MFMA16(a0, b0, acc[0][0]);
        acc[0][1] = MFMA16(a0, b1, acc[0][1]);
        acc[1][0] = MFMA16(a1, b0, acc[1][0]);
        acc[1][1] = MFMA16(a1, b1, acc[1][1]);
    }
    float* pp = part + (size_t)blockIdx.z * M * N;
#pragma unroll
    for (int mi = 0; mi < 2; ++mi)
#pragma unroll
        for (int ni = 0; ni < 2; ++ni)
#pragma unroll
            for (int j = 0; j < 4; ++j) {
                int row = m0 + wr * 32 + mi * 16 + lg * 4 + j;
                int col = n0 + wc * 32 + ni * 16 + lr;
                pp[(size_t)row * N + col] = acc[mi][ni][j];
            }
}

// sum splits + bias + leaky -> bf16 and/or fp32
__global__ void k_epilogue(const float* __restrict__ part, const float* __restrict__ bias,
                           short* __restrict__ out_b, float* __restrict__ out_f,
                           int MN, int N, int S, float slope) {
    int i = (blockIdx.x * 256 + threadIdx.x) * 4;
    if (i >= MN) return;
    float4 v = *(const float4*)(part + i);
    for (int s = 1; s < S; ++s) {
        float4 p = *(const float4*)(part + (size_t)s * MN + i);
        v.x += p.x; v.y += p.y; v.z += p.z; v.w += p.w;
    }
    float4 b = *(const float4*)(bias + (i % N));
    v.x += b.x; v.y += b.y; v.z += b.z; v.w += b.w;
    v.x = (v.x >= 0.f) ? v.x : v.x * slope;
    v.y = (v.y >= 0.f) ? v.y : v.y * slope;
    v.z = (v.z >= 0.f) ? v.z : v.z * slope;
    v.w = (v.w >= 0.f) ? v.w : v.w * slope;
    if (out_b) {
        out_b[i + 0] = f2bs(v.x); out_b[i + 1] = f2bs(v.y);
        out_b[i + 2] = f2bs(v.z); out_b[i + 3] = f2bs(v.w);
    }
    if (out_f) *(float4*)(out_f + i) = v;
}

// ---------------- LSTM step (fp32, unchanged math; nh stored bf16) ----------------
__global__ void k_lstm_step(const float* __restrict__ P, const float* __restrict__ WhhT,
                            const float* __restrict__ bhh, const int* __restrict__ done,
                            const float* __restrict__ h_in, float* __restrict__ h_out,
                            float* __restrict__ c, short* __restrict__ nh, int t) {
    int b = blockIdx.x >> 3;
    int hc = blockIdx.x & 7;
    int tid = threadIdx.x;
    __shared__ float hs[512];
    __shared__ float gs[4][64];
    float m = 1.0f - (float)done[t * 32 + b];
    for (int i = tid; i < 512; i += 128) hs[i] = h_in[b * 512 + i] * m;
    __syncthreads();
    int gate = tid >> 5;
    int hp = (tid & 31) * 2;
    int j0 = gate * 512 + hc * 64 + hp;
    float acc0 = bhh[j0], acc1 = bhh[j0 + 1];
#pragma unroll 4
    for (int k = 0; k < 512; k += 4) {
        float4 h4 = *(const float4*)(&hs[k]);
        const float* hv = (const float*)&h4;
#pragma unroll
        for (int q = 0; q < 4; ++q) {
            float2 w2 = *(const float2*)(WhhT + (size_t)(k + q) * 2048 + j0);
            acc0 += hv[q] * w2.x;
            acc1 += hv[q] * w2.y;
        }
    }
    int row = t * 32 + b;
    acc0 += P[(size_t)row * 2048 + j0];
    acc1 += P[(size_t)row * 2048 + j0 + 1];
    gs[gate][hp] = acc0;
    gs[gate][hp + 1] = acc1;
    __syncthreads();
    if (tid < 64) {
        int hi = hc * 64 + tid;
        float ig = 1.f / (1.f + expf(-gs[0][tid]));
        float fg = 1.f / (1.f + expf(-gs[1][tid]));
        float gg = tanhf(gs[2][tid]);
        float og = 1.f / (1.f + expf(-gs[3][tid]));
        float cnew = fg * (c[b * 512 + hi] * m) + ig * gg;
        float hnew = og * tanhf(cnew);
        c[b * 512 + hi] = cnew;
        h_out[b * 512 + hi] = hnew;
        nh[(size_t)row * 512 + hi] = f2bs(hnew);
    }
}

// ---------------- small heads: logits [512][8], value [512] ----------------
// wave per output; 4608 outputs = 512 * 9 (cols 0..7 logits from aA, col 8 value from aC)
__global__ void k_heads(const short* __restrict__ aA, const short* __restrict__ aC,
                        const short* __restrict__ A2b, const float* __restrict__ Ab2,
                        const short* __restrict__ C2b, const float* __restrict__ Cb2,
                        float* __restrict__ out) {
    int idx = blockIdx.x * 4 + (threadIdx.x >> 6);
    int l = threadIdx.x & 63;
    if (idx >= 4608) return;
    int row = idx / 9, col = idx % 9;
    const short* act = (col < 8) ? (aA + (size_t)row * 512) : (aC + (size_t)row * 512);
    const short* wr  = (col < 8) ? (A2b + (size_t)col * 512) : C2b;
    short8 a = *(const short8*)(act + l * 8);
    short8 wv = *(const short8*)(wr + l * 8);
    float s = 0.f;
#pragma unroll
    for (int q = 0; q < 8; ++q) s += bs2f(a[q]) * bs2f(wv[q]);
#pragma unroll
    for (int off = 32; off > 0; off >>= 1) s += __shfl_xor(s, off, 64);
    if (l == 0) {
        if (col < 8) out[row * 8 + col] = s + Ab2[col];
        else out[4096 + row] = s + Cb2[0];
    }
}

// ---------------- launch ----------------

extern "C" void kernel_launch(void* const* d_in, const int* in_sizes, int n_in,
                              void* d_out, int out_size, void* d_ws, size_t ws_size,
                              hipStream_t stream) {
    (void)in_sizes; (void)n_in; (void)out_size; (void)ws_size;
    const float* x    = (const float*)d_in[0];
    const int*   done = (const int*)  d_in[1];
    const float* h0   = (const float*)d_in[2];
    const float* c0   = (const float*)d_in[3];
    const float* w1   = (const float*)d_in[4];
    const float* b1   = (const float*)d_in[5];
    const float* w2   = (const float*)d_in[6];
    const float* b2   = (const float*)d_in[7];
    const float* w3   = (const float*)d_in[8];
    const float* b3   = (const float*)d_in[9];
    const float* fcW  = (const float*)d_in[10];
    const float* fcb  = (const float*)d_in[11];
    const float* Wih  = (const float*)d_in[12];
    const float* Whh  = (const float*)d_in[13];
    const float* bih  = (const float*)d_in[14];
    const float* bhh  = (const float*)d_in[15];
    const float* A1   = (const float*)d_in[16];
    const float* Ab1  = (const float*)d_in[17];
    const float* A2   = (const float*)d_in[18];
    const float* Ab2  = (const float*)d_in[19];
    const float* C1   = (const float*)d_in[20];
    const float* Cb1  = (const float*)d_in[21];
    const float* C2   = (const float*)d_in[22];
    const float* Cb2  = (const float*)d_in[23];
    float* out = (float*)d_out;

    char* wsp = (char*)d_ws;
    auto alloc = [&](size_t bytes) {
        char* p = wsp; wsp += (bytes + 255) & ~(size_t)255; return p;
    };
    short* a1s  = (short*)alloc(18530304ull * 2);  // [512*29*39][32] NHWC
    short* a2s  = (short*)alloc(7667712ull * 2);   // [512*13*18][64]
    short* a3s  = (short*)alloc(5767168ull * 2);   // [512*176][64]
    short* hfc  = (short*)alloc(262144ull * 2);    // [512][512]
    float* P    = (float*)alloc(1048576ull * 4);   // [512][2048]
    float* WhhT = (float*)alloc(1048576ull * 4);
    float* hA   = (float*)alloc(16384ull * 4);
    float* hB   = (float*)alloc(16384ull * 4);
    float* cS   = (float*)alloc(16384ull * 4);
    short* nh   = (short*)alloc(262144ull * 2);
    short* aA   = (short*)alloc(262144ull * 2);
    short* aC   = (short*)alloc(262144ull * 2);
    float* part = (float*)alloc(1048576ull * 4);   // max(4*512*512, 512*2048) fp32
    short* wc1  = (short*)alloc(6144ull * 2);
    short* wc2  = (short*)alloc(32768ull * 2);
    short* wc3  = (short*)alloc(36864ull * 2);
    short* fcwr = (short*)alloc(5767168ull * 2);
    short* wihb = (short*)alloc(1048576ull * 2);
    short* a1b  = (short*)alloc(262144ull * 2);
    short* c1b  = (short*)alloc(262144ull * 2);
    short* a2b  = (short*)alloc(4096ull * 2);
    short* c2b  = (short*)alloc(512ull * 2);

    // prep
    k_cvt<<<6, 256, 0, stream>>>(w1, wc1, 1536);           // order matches (ic*64+kh*8+kw)
    k_prep_wc2<<<128, 256, 0, stream>>>(w2, wc2);
    k_prep_wc3<<<144, 256, 0, stream>>>(w3, wc3);
    k_prep_fcw<<<22528, 256, 0, stream>>>(fcW, fcwr);
    k_cvt<<<1024, 256, 0, stream>>>(Wih, wihb, 262144);
    k_cvt<<<256, 256, 0, stream>>>(A1, a1b, 65536);
    k_cvt<<<256, 256, 0, stream>>>(C1, c1b, 65536);
    k_cvt<<<4, 256, 0, stream>>>(A2, a2b, 1024);
    k_cvt<<<1, 256, 0, stream>>>(C2, c2b, 128);
    k_init_state<<<64, 256, 0, stream>>>(h0, c0, hA, cS);
    k_transpose_whh<<<1024, 256, 0, stream>>>(Whh, WhhT);

    // convs
    k_conv1_mfma<<<512, 256, 0, stream>>>(x, wc1, b1, a1s);
    k_conv2_mfma<<<512, 256, 0, stream>>>(a1s, wc2, b2, a2s);
    k_conv3_mfma<<<512, 256, 0, stream>>>(a2s, wc3, b3, a3s);

    // FC: [512][11264] @ fcwr^T, split-K 4
    k_gemm_mfma<<<dim3(8, 8, 4), 256, 0, stream>>>(a3s, fcwr, part, 512, 512, 11264, 2816);
    k_epilogue<<<256, 256, 0, stream>>>(part, fcb, hfc, nullptr, 262144, 512, 4, 0.2f);

    // P = hfc @ Wih^T + bih (fp32 out)
    k_gemm_mfma<<<dim3(32, 8, 1), 256, 0, stream>>>(hfc, wihb, part, 512, 2048, 512, 512);
    k_epilogue<<<1024, 256, 0, stream>>>(part, bih, nullptr, P, 1048576, 2048, 1, 1.0f);

    for (int t = 0; t < 16; ++t) {
        const float* hin = (t & 1) ? hB : hA;
        float* hout      = (t & 1) ? hA : hB;
        k_lstm_step<<<256, 128, 0, stream>>>(P, WhhT, bhh, done, hin, hout, cS, nh, t);
    }

    // heads
    k_gemm_mfma<<<dim3(8, 8, 1), 256, 0, stream>>>(nh, a1b, part, 512, 512, 512, 512);
    k_epilogue<<<256, 256, 0, stream>>>(part, Ab1, aA, nullptr, 262144, 512, 1, 0.01f);
    k_gemm_mfma<<<dim3(8, 8, 1), 256, 0, stream>>>(nh, c1b, part, 512, 512, 512, 512);
    k_epilogue<<<256, 256, 0, stream>>>(part, Cb1, aC, nullptr, 262144, 512, 1, 0.01f);
    k_heads<<<1152, 256, 0, stream>>>(aA, aC, a2b, Ab2, c2b, Cb2, out);

    k_states_out<<<64, 256, 0, stream>>>(hA, cS, out + 4608, out + 20992);
}

// Round 4
// 288.536 us; speedup vs baseline: 4.0699x; 2.1174x over previous
//
#include <hip/hip_runtime.h>
#include <hip/hip_bf16.h>
#include <math.h>

using short8 = __attribute__((ext_vector_type(8))) short;   // 8 bf16 (4 VGPR)
using f32x4  = __attribute__((ext_vector_type(4))) float;   // MFMA acc

#define MFMA16(a, b, c) __builtin_amdgcn_mfma_f32_16x16x32_bf16(a, b, c, 0, 0, 0)

__device__ __forceinline__ short f2bs(float f) {
    __hip_bfloat16 h = __float2bfloat16(f);          // RNE
    return __builtin_bit_cast(short, h);
}
__device__ __forceinline__ float bs2f(short s) {
    return __uint_as_float(((unsigned)(unsigned short)s) << 16);
}

// ---------------- prep kernels ----------------

__global__ void k_cvt(const float* __restrict__ in, short* __restrict__ out, int n4) {
    int i = blockIdx.x * 256 + threadIdx.x;
    if (i >= n4) return;
    float4 v = *(const float4*)(in + i * 4);
    out[i * 4 + 0] = f2bs(v.x); out[i * 4 + 1] = f2bs(v.y);
    out[i * 4 + 2] = f2bs(v.z); out[i * 4 + 3] = f2bs(v.w);
}

// w2 [64][32][4][4] -> Wc2 [oc][kh*128 + kw*32 + ic]
__global__ void k_prep_wc2(const float* __restrict__ w, short* __restrict__ o) {
    int i = blockIdx.x * 256 + threadIdx.x;
    if (i >= 32768) return;
    int oc = i >> 9, col = i & 511;
    int kh = col >> 7, kw = (col >> 5) & 3, ic = col & 31;
    o[i] = f2bs(w[((oc * 32 + ic) * 4 + kh) * 4 + kw]);
}

// w3 [64][64][3][3] -> Wc3 [oc][kh*192 + kw*64 + ic]
__global__ void k_prep_wc3(const float* __restrict__ w, short* __restrict__ o) {
    int i = blockIdx.x * 256 + threadIdx.x;
    if (i >= 36864) return;
    int oc = i / 576, col = i % 576;
    int kh = col / 192, r = col % 192, kw = r >> 6, ic = r & 63;
    o[i] = f2bs(w[((oc * 64 + ic) * 3 + kh) * 3 + kw]);
}

// fcW [512][11264] (K = oc*176+pix) -> fcWr [512][pix*64+oc] via LDS transpose, 1 row/block
__global__ void k_prep_fcw2(const float* __restrict__ w, short* __restrict__ o) {
    __shared__ short t[176 * 76];
    int r = blockIdx.x, tid = threadIdx.x;
    for (int it = 0; it < 11; ++it) {
        int c4 = it * 256 + tid;                 // 2816 float4s exactly
        float4 v = *(const float4*)(w + (size_t)r * 11264 + c4 * 4);
        int c = c4 * 4;
        int oc = c / 176, pix = c % 176;         // 4 consecutive pix share oc (176%4==0)
        t[(pix + 0) * 76 + oc] = f2bs(v.x);
        t[(pix + 1) * 76 + oc] = f2bs(v.y);
        t[(pix + 2) * 76 + oc] = f2bs(v.z);
        t[(pix + 3) * 76 + oc] = f2bs(v.w);
    }
    __syncthreads();
    for (int it = 0; it < 6; ++it) {
        int j8 = it * 256 + tid;
        if (j8 < 1408) {
            int j = j8 * 8, pix = j >> 6, oc0 = j & 63;
            const short* tp = &t[pix * 76 + oc0];
            short8 v;
            ((uint2*)&v)[0] = *(const uint2*)tp;
            ((uint2*)&v)[1] = *(const uint2*)(tp + 4);
            *(short8*)&o[(size_t)r * 11264 + j] = v;
        }
    }
}

__global__ void k_init_c(const float* __restrict__ c0, float* __restrict__ cf) {
    int i = blockIdx.x * 256 + threadIdx.x;
    if (i < 16384) cf[i] = c0[i];
}

__global__ void k_prep_hm(const float* __restrict__ h0, const int* __restrict__ done,
                          short* __restrict__ hm) {
    int i = blockIdx.x * 256 + threadIdx.x;
    if (i < 16384) {
        float m = 1.f - (float)done[i >> 9];
        hm[i] = f2bs(h0[i] * m);
    }
}

__global__ void k_bias2(const float* __restrict__ a, const float* __restrict__ b,
                        float* __restrict__ o) {
    int i = blockIdx.x * 256 + threadIdx.x;
    if (i < 2048) o[i] = a[i] + b[i];
}

__global__ void k_states_out(const float* __restrict__ hf, const float* __restrict__ cf,
                             float* __restrict__ oh, float* __restrict__ oc) {
    int i = blockIdx.x * 256 + threadIdx.x;
    if (i < 16384) { oh[i] = hf[i]; oc[i] = cf[i]; }
}

// ---------------- conv1: x[512][3][120][160] f32 -> a1 NHWC [n][1131 px][32] bf16 ----------------
// block = (n, quad of 4 oh rows). LDS: 20 input rows x 3 ic, bf16. Wave-local C tiles.
__global__ void __launch_bounds__(256) k_conv1_v2(const float* __restrict__ x,
                                                  const short* __restrict__ Wc,
                                                  const float* __restrict__ bias,
                                                  short* __restrict__ y) {
    __shared__ short xs[9600];          // [3 ic][20 rows][160]
    __shared__ short ct[4][512];        // per-wave [16 px][32 oc]
    const int bid = blockIdx.x;
    const int n = bid >> 3, q = bid & 7;
    const int tid = threadIdx.x;
    const int w = tid >> 6, l = tid & 63;
    const int lr = l & 15, lg = l >> 4;
    short8 bf[6][2];
#pragma unroll
    for (int ks = 0; ks < 6; ++ks)
#pragma unroll
        for (int nf = 0; nf < 2; ++nf)
            bf[ks][nf] = *(const short8*)&Wc[(nf * 16 + lr) * 192 + ks * 32 + lg * 8];
    float bc[2] = {bias[lr], bias[16 + lr]};
    const float* xb = x + (size_t)n * 57600;
    for (int ic = 0; ic < 3; ++ic) {
        for (int it = 0; it < 7; ++it) {
            int idx2 = it * 256 + tid;           // float2 index, 1600 per ic
            if (idx2 < 1600) {
                int goff = q * 2560 + idx2 * 2;
                if (goff > 19198) goff = 19198;  // clamp (last quad)
                float2 v = *(const float2*)(xb + ic * 19200 + goff);
                unsigned pk = ((unsigned)(unsigned short)f2bs(v.x)) |
                              (((unsigned)(unsigned short)f2bs(v.y)) << 16);
                *(unsigned*)&xs[ic * 3200 + idx2 * 2] = pk;
            }
        }
    }
    __syncthreads();
    for (int i = 0; i < 3; ++i) {
        int t = w * 3 + i;
        int p = t * 16 + lr;
        int pc = p < 156 ? p : 155;
        int ohr = pc / 39, ow = pc - ohr * 39;
        f32x4 acc[2] = {};
#pragma unroll
        for (int ks = 0; ks < 6; ++ks) {
            int ic = ks >> 1, kh4 = (ks & 1) * 4;
            int ih = ohr * 4 + kh4 + lg;
            const short* ap = &xs[(ic * 20 + ih) * 160 + ow * 4];
            short8 a;
            ((uint2*)&a)[0] = *(const uint2*)ap;
            ((uint2*)&a)[1] = *(const uint2*)(ap + 4);
            acc[0] = MFMA16(a, bf[ks][0], acc[0]);
            acc[1] = MFMA16(a, bf[ks][1], acc[1]);
        }
#pragma unroll
        for (int nf = 0; nf < 2; ++nf)
#pragma unroll
            for (int j = 0; j < 4; ++j)
                ct[w][(lg * 4 + j) * 32 + nf * 16 + lr] =
                    f2bs(fmaxf(acc[nf][j] + bc[nf], 0.f));
        asm volatile("s_waitcnt lgkmcnt(0)" ::: "memory");
        int row = l >> 2, c8 = (l & 3) * 8;
        short8 v = *(const short8*)&ct[w][row * 32 + c8];
        int pg = t * 16 + row;
        if (pg < 156 && (q < 7 || pg < 39))
            *(short8*)&y[((size_t)n * 1131 + q * 156 + pg) * 32 + c8] = v;
        asm volatile("s_waitcnt lgkmcnt(0)" ::: "memory");
    }
}

// ---------------- conv2: a1 NHWC -> a2 NHWC [n][234 px][64] ----------------
// block = image. Whole image in swizzled LDS; weights in VGPRs (nf-half per wave).
__global__ void __launch_bounds__(256, 2) k_conv2_v2(const short* __restrict__ a1,
                                                     const short* __restrict__ Wc,
                                                     const float* __restrict__ bias,
                                                     short* __restrict__ y) {
    __shared__ short img[36192];        // [29][39][32] swizzled
    __shared__ short ct[2][1024];       // [parity][16 px][64 oc]
    const int n = blockIdx.x, tid = threadIdx.x;
    const int w = tid >> 6, l = tid & 63, lr = l & 15, lg = l >> 4;
    const int par = w >> 1, nfh = w & 1;
    short8 bfg[16][2];
#pragma unroll
    for (int ks = 0; ks < 16; ++ks)
#pragma unroll
        for (int q2 = 0; q2 < 2; ++q2)
            bfg[ks][q2] = *(const short8*)&Wc[(nfh * 32 + q2 * 16 + lr) * 512 + ks * 32 + lg * 8];
    float bc[2] = {bias[nfh * 32 + lr], bias[nfh * 32 + 16 + lr]};
    const short* src = a1 + (size_t)n * 36192;
    for (int it = 0; it < 18; ++it) {
        int i8 = it * 256 + tid;
        if (i8 < 4524) {
            short8 v = *(const short8*)(src + i8 * 8);
            int b = i8 * 16;
            b ^= ((b >> 7) & 7) << 4;
            *(short8*)((char*)img + b) = v;
        }
    }
    __syncthreads();
    for (int t = par; t < 16; t += 2) {
        int p = t * 16 + lr;
        int pc = p < 234 ? p : 233;
        int oh = pc / 18, ow = pc - oh * 18;
        int base = (oh * 2 * 39 + ow * 2) * 64 + lg * 16;
        f32x4 acc[2] = {};
#pragma unroll
        for (int ks = 0; ks < 16; ++ks) {
            int kh = ks >> 2, kw = ks & 3;
            int b = base + (kh * 39 + kw) * 64;
            b ^= ((b >> 7) & 7) << 4;
            short8 a = *(const short8*)((const char*)img + b);
            acc[0] = MFMA16(a, bfg[ks][0], acc[0]);
            acc[1] = MFMA16(a, bfg[ks][1], acc[1]);
        }
#pragma unroll
        for (int q2 = 0; q2 < 2; ++q2)
#pragma unroll
            for (int j = 0; j < 4; ++j)
                ct[par][(lg * 4 + j) * 64 + nfh * 32 + q2 * 16 + lr] =
                    f2bs(fmaxf(acc[q2][j] + bc[q2], 0.f));
        __syncthreads();
        int li = nfh * 64 + l;
        int row = li >> 3, c8 = (li & 7) * 8;
        short8 v = *(const short8*)&ct[par][row * 64 + c8];
        int pg = t * 16 + row;
        if (pg < 234)
            *(short8*)&y[((size_t)n * 234 + pg) * 64 + c8] = v;
        __syncthreads();
    }
}

// ---------------- conv3: a2 NHWC -> a3 NHWC [n][176 px][64] ----------------
__global__ void __launch_bounds__(256, 2) k_conv3_v2(const short* __restrict__ a2,
                                                     const short* __restrict__ Wc,
                                                     const float* __restrict__ bias,
                                                     short* __restrict__ y) {
    __shared__ short img[14976];        // [13][18][64] swizzled
    __shared__ short ct[2][1024];
    const int n = blockIdx.x, tid = threadIdx.x;
    const int w = tid >> 6, l = tid & 63, lr = l & 15, lg = l >> 4;
    const int par = w >> 1, nfh = w & 1;
    short8 bfg[18][2];
#pragma unroll
    for (int ks = 0; ks < 18; ++ks)
#pragma unroll
        for (int q2 = 0; q2 < 2; ++q2)
            bfg[ks][q2] = *(const short8*)&Wc[(nfh * 32 + q2 * 16 + lr) * 576 + ks * 32 + lg * 8];
    float bc[2] = {bias[nfh * 32 + lr], bias[nfh * 32 + 16 + lr]};
    const short* src = a2 + (size_t)n * 14976;
    for (int it = 0; it < 8; ++it) {
        int i8 = it * 256 + tid;
        if (i8 < 1872) {
            short8 v = *(const short8*)(src + i8 * 8);
            int b = i8 * 16;
            b ^= ((b >> 7) & 7) << 4;
            *(short8*)((char*)img + b) = v;
        }
    }
    __syncthreads();
    for (int t = par; t < 12; t += 2) {
        int p = t * 16 + lr;
        int pc = p < 176 ? p : 175;
        int oh = pc >> 4, ow = pc & 15;
        int base = (oh * 18 + ow) * 128 + lg * 16;
        f32x4 acc[2] = {};
#pragma unroll
        for (int ks = 0; ks < 18; ++ks) {
            int kh = ks / 6, r6 = ks % 6, kw = r6 >> 1, ich = r6 & 1;
            int b = base + (kh * 18 + kw) * 128 + ich * 64;
            b ^= ((b >> 7) & 7) << 4;
            short8 a = *(const short8*)((const char*)img + b);
            acc[0] = MFMA16(a, bfg[ks][0], acc[0]);
            acc[1] = MFMA16(a, bfg[ks][1], acc[1]);
        }
#pragma unroll
        for (int q2 = 0; q2 < 2; ++q2)
#pragma unroll
            for (int j = 0; j < 4; ++j)
                ct[par][(lg * 4 + j) * 64 + nfh * 32 + q2 * 16 + lr] =
                    f2bs(fmaxf(acc[q2][j] + bc[q2], 0.f));
        __syncthreads();
        int li = nfh * 64 + l;
        int row = li >> 3, c8 = (li & 7) * 8;
        short8 v = *(const short8*)&ct[par][row * 64 + c8];
        int pg = t * 16 + row;
        if (pg < 176)
            *(short8*)&y[((size_t)n * 176 + pg) * 64 + c8] = v;
        __syncthreads();
    }
}

// ---------------- MFMA GEMM core (unchanged): part[z][M][N] = A @ W^T ----------------
__global__ void k_gemm_mfma(const short* __restrict__ A, const short* __restrict__ W,
                            float* __restrict__ part, int M, int N, int K, int kPerSplit) {
    __shared__ short As[64 * 40];
    __shared__ short Ws[64 * 40];
    const int tid = threadIdx.x;
    const int m0 = blockIdx.y * 64, n0 = blockIdx.x * 64;
    const int k0s = blockIdx.z * kPerSplit, k0e = k0s + kPerSplit;
    const int w = tid >> 6, l = tid & 63;
    const int wr = w >> 1, wc = w & 1;
    const int sr = tid >> 2, sc = tid & 3;
    const int lr = l & 15, lg = l >> 4;
    f32x4 acc[2][2] = {};
    for (int k0 = k0s; k0 < k0e; k0 += 32) {
        short8 av = *(const short8*)(A + (size_t)(m0 + sr) * K + k0 + sc * 8);
        short8 wv = *(const short8*)(W + (size_t)(n0 + sr) * K + k0 + sc * 8);
        __syncthreads();
        *(short8*)&As[sr * 40 + sc * 8] = av;
        *(short8*)&Ws[sr * 40 + sc * 8] = wv;
        __syncthreads();
        int cb = lg * 8;
        short8 a0 = *(const short8*)&As[(wr * 32 + lr) * 40 + cb];
        short8 a1 = *(const short8*)&As[(wr * 32 + 16 + lr) * 40 + cb];
        short8 b0 = *(const short8*)&Ws[(wc * 32 + lr) * 40 + cb];
        short8 b1 = *(const short8*)&Ws[(wc * 32 + 16 + lr) * 40 + cb];
        acc[0][0] = MFMA16(a0, b0, acc[0][0]);
        acc[0][1] = MFMA16(a0, b1, acc[0][1]);
        acc[1][0] = MFMA16(a1, b0, acc[1][0]);
        acc[1][1] = MFMA16(a1, b1, acc[1][1]);
    }
    float* pp = part + (size_t)blockIdx.z * M * N;
#pragma unroll
    for (int mi = 0; mi < 2; ++mi)
#pragma unroll
        for (int ni = 0; ni < 2; ++ni)
#pragma unroll
            for (int j = 0; j < 4; ++j) {
                int row = m0 + wr * 32 + mi * 16 + lg * 4 + j;
                int col = n0 + wc * 32 + ni * 16 + lr;
                pp[(size_t)row * N + col] = acc[mi][ni][j];
            }
}

__global__ void k_epilogue(const float* __restrict__ part, const float* __restrict__ bias,
                           short* __restrict__ out_b, float* __restrict__ out_f,
                           int MN, int N, int S, float slope) {
    int i = (blockIdx.x * 256 + threadIdx.x) * 4;
    if (i >= MN) return;
    float4 v = *(const float4*)(part + i);
    for (int s = 1; s < S; ++s) {
        float4 p = *(const float4*)(part + (size_t)s * MN + i);
        v.x += p.x; v.y += p.y; v.z += p.z; v.w += p.w;
    }
    float4 b = *(const float4*)(bias + (i % N));
    v.x += b.x; v.y += b.y; v.z += b.z; v.w += b.w;
    v.x = (v.x >= 0.f) ? v.x : v.x * slope;
    v.y = (v.y >= 0.f) ? v.y : v.y * slope;
    v.z = (v.z >= 0.f) ? v.z : v.z * slope;
    v.w = (v.w >= 0.f) ? v.w : v.w * slope;
    if (out_b) {
        out_b[i + 0] = f2bs(v.x); out_b[i + 1] = f2bs(v.y);
        out_b[i + 2] = f2bs(v.z); out_b[i + 3] = f2bs(v.w);
    }
    if (out_f) *(float4*)(out_f + i) = v;
}

// ---------------- fused LSTM step: 32 blocks (16 hidden cols each), 4 gate-waves ----------------
// P contains x@Wih + bih + bhh (fp32). hmIn = bf16 pre-masked h. Updates cS in place.
__global__ void k_lstm2(const float* __restrict__ P, const short* __restrict__ Whhb,
                        const int* __restrict__ done, const short* __restrict__ hmIn,
                        short* __restrict__ hmOut, float* __restrict__ cS,
                        short* __restrict__ nh, float* __restrict__ hT, int t) {
    __shared__ short hs[32 * 520];
    __shared__ float gb[4][512];
    const int hb = blockIdx.x;
    const int tid = threadIdx.x, w = tid >> 6, l = tid & 63, lr = l & 15, lg = l >> 4;
    for (int it = 0; it < 8; ++it) {
        int i8 = it * 256 + tid;                 // 2048 short8 total
        short8 v = *(const short8*)(hmIn + i8 * 8);
        int row = i8 >> 6, col = (i8 & 63) * 8;
        *(short8*)&hs[row * 520 + col] = v;
    }
    short8 bfg[16];
    const short* wrow = Whhb + (size_t)(w * 512 + hb * 16 + lr) * 512;
#pragma unroll
    for (int ks = 0; ks < 16; ++ks) bfg[ks] = *(const short8*)(wrow + ks * 32 + lg * 8);
    __syncthreads();
    f32x4 acc[2] = {};
#pragma unroll
    for (int ks = 0; ks < 16; ++ks) {
        short8 a0 = *(const short8*)&hs[lr * 520 + ks * 32 + lg * 8];
        short8 a1 = *(const short8*)&hs[(16 + lr) * 520 + ks * 32 + lg * 8];
        acc[0] = MFMA16(a0, bfg[ks], acc[0]);
        acc[1] = MFMA16(a1, bfg[ks], acc[1]);
    }
#pragma unroll
    for (int mt = 0; mt < 2; ++mt)
#pragma unroll
        for (int j = 0; j < 4; ++j) {
            int batch = mt * 16 + lg * 4 + j;
            float v = acc[mt][j] + P[(size_t)(t * 32 + batch) * 2048 + w * 512 + hb * 16 + lr];
            gb[w][batch * 16 + lr] = v;
        }
    __syncthreads();
#pragma unroll
    for (int q2 = 0; q2 < 2; ++q2) {
        int idx = tid * 2 + q2;
        int batch = idx >> 4, h = idx & 15;
        float gi = gb[0][idx], gf = gb[1][idx], gg = gb[2][idx], go = gb[3][idx];
        float m = 1.f - (float)done[t * 32 + batch];
        float ig = 1.f / (1.f + expf(-gi));
        float fg = 1.f / (1.f + expf(-gf));
        float gt = tanhf(gg);
        float og = 1.f / (1.f + expf(-go));
        int ci = batch * 512 + hb * 16 + h;
        float cn = fg * (cS[ci] * m) + ig * gt;
        float hn = og * tanhf(cn);
        cS[ci] = cn;
        nh[(size_t)(t * 32 + batch) * 512 + hb * 16 + h] = f2bs(hn);
        if (t < 15) {
            float m2 = 1.f - (float)done[(t + 1) * 32 + batch];
            hmOut[ci] = f2bs(hn * m2);
        } else {
            hT[ci] = hn;
        }
    }
}

// ---------------- small heads ----------------
__global__ void k_heads(const short* __restrict__ aA, const short* __restrict__ aC,
                        const short* __restrict__ A2b, const float* __restrict__ Ab2,
                        const short* __restrict__ C2b, const float* __restrict__ Cb2,
                        float* __restrict__ out) {
    int idx = blockIdx.x * 4 + (threadIdx.x >> 6);
    int l = threadIdx.x & 63;
    if (idx >= 4608) return;
    int row = idx / 9, col = idx % 9;
    const short* act = (col < 8) ? (aA + (size_t)row * 512) : (aC + (size_t)row * 512);
    const short* wr  = (col < 8) ? (A2b + (size_t)col * 512) : C2b;
    short8 a = *(const short8*)(act + l * 8);
    short8 wv = *(const short8*)(wr + l * 8);
    float s = 0.f;
#pragma unroll
    for (int q = 0; q < 8; ++q) s += bs2f(a[q]) * bs2f(wv[q]);
#pragma unroll
    for (int off = 32; off > 0; off >>= 1) s += __shfl_xor(s, off, 64);
    if (l == 0) {
        if (col < 8) out[row * 8 + col] = s + Ab2[col];
        else out[4096 + row] = s + Cb2[0];
    }
}

// ---------------- launch ----------------

extern "C" void kernel_launch(void* const* d_in, const int* in_sizes, int n_in,
                              void* d_out, int out_size, void* d_ws, size_t ws_size,
                              hipStream_t stream) {
    (void)in_sizes; (void)n_in; (void)out_size; (void)ws_size;
    const float* x    = (const float*)d_in[0];
    const int*   done = (const int*)  d_in[1];
    const float* h0   = (const float*)d_in[2];
    const float* c0   = (const float*)d_in[3];
    const float* w1   = (const float*)d_in[4];
    const float* b1   = (const float*)d_in[5];
    const float* w2   = (const float*)d_in[6];
    const float* b2   = (const float*)d_in[7];
    const float* w3   = (const float*)d_in[8];
    const float* b3   = (const float*)d_in[9];
    const float* fcW  = (const float*)d_in[10];
    const float* fcb  = (const float*)d_in[11];
    const float* Wih  = (const float*)d_in[12];
    const float* Whh  = (const float*)d_in[13];
    const float* bih  = (const float*)d_in[14];
    const float* bhh  = (const float*)d_in[15];
    const float* A1   = (const float*)d_in[16];
    const float* Ab1  = (const float*)d_in[17];
    const float* A2   = (const float*)d_in[18];
    const float* Ab2  = (const float*)d_in[19];
    const float* C1   = (const float*)d_in[20];
    const float* Cb1  = (const float*)d_in[21];
    const float* C2   = (const float*)d_in[22];
    const float* Cb2  = (const float*)d_in[23];
    float* out = (float*)d_out;

    char* wsp = (char*)d_ws;
    auto alloc = [&](size_t bytes) {
        char* p = wsp; wsp += (bytes + 255) & ~(size_t)255; return p;
    };
    short* a1s  = (short*)alloc(18530304ull * 2);  // [512][1131][32]
    short* a2s  = (short*)alloc(7667712ull * 2);   // [512][234][64]
    short* a3s  = (short*)alloc(5767168ull * 2);   // [512][176][64]
    short* hfc  = (short*)alloc(262144ull * 2);    // [512][512]
    float* P    = (float*)alloc(1048576ull * 4);   // [512][2048]
    short* whhb = (short*)alloc(1048576ull * 2);   // Whh bf16 [2048][512]
    float* hA   = (float*)alloc(16384ull * 4);     // final hT f32
    float* cS   = (float*)alloc(16384ull * 4);
    short* hm0  = (short*)alloc(16384ull * 2);
    short* hm1  = (short*)alloc(16384ull * 2);
    short* nh   = (short*)alloc(262144ull * 2);
    short* aA   = (short*)alloc(262144ull * 2);
    short* aC   = (short*)alloc(262144ull * 2);
    float* part = (float*)alloc(1048576ull * 4);
    short* wc1  = (short*)alloc(6144ull * 2);
    short* wc2  = (short*)alloc(32768ull * 2);
    short* wc3  = (short*)alloc(36864ull * 2);
    short* fcwr = (short*)alloc(5767168ull * 2);
    short* wihb = (short*)alloc(1048576ull * 2);
    short* a1b  = (short*)alloc(262144ull * 2);
    short* c1b  = (short*)alloc(262144ull * 2);
    short* a2b  = (short*)alloc(4096ull * 2);
    short* c2b  = (short*)alloc(512ull * 2);
    float* bias2= (float*)alloc(2048ull * 4);

    // prep
    k_cvt<<<6, 256, 0, stream>>>(w1, wc1, 1536);
    k_prep_wc2<<<128, 256, 0, stream>>>(w2, wc2);
    k_prep_wc3<<<144, 256, 0, stream>>>(w3, wc3);
    k_prep_fcw2<<<512, 256, 0, stream>>>(fcW, fcwr);
    k_cvt<<<1024, 256, 0, stream>>>(Wih, wihb, 262144);
    k_cvt<<<1024, 256, 0, stream>>>(Whh, whhb, 262144);
    k_cvt<<<256, 256, 0, stream>>>(A1, a1b, 65536);
    k_cvt<<<256, 256, 0, stream>>>(C1, c1b, 65536);
    k_cvt<<<4, 256, 0, stream>>>(A2, a2b, 1024);
    k_cvt<<<1, 256, 0, stream>>>(C2, c2b, 128);
    k_init_c<<<64, 256, 0, stream>>>(c0, cS);
    k_prep_hm<<<64, 256, 0, stream>>>(h0, done, hm0);
    k_bias2<<<8, 256, 0, stream>>>(bih, bhh, bias2);

    // convs
    k_conv1_v2<<<4096, 256, 0, stream>>>(x, wc1, b1, a1s);
    k_conv2_v2<<<512, 256, 0, stream>>>(a1s, wc2, b2, a2s);
    k_conv3_v2<<<512, 256, 0, stream>>>(a2s, wc3, b3, a3s);

    // FC: split-K 4
    k_gemm_mfma<<<dim3(8, 8, 4), 256, 0, stream>>>(a3s, fcwr, part, 512, 512, 11264, 2816);
    k_epilogue<<<256, 256, 0, stream>>>(part, fcb, hfc, nullptr, 262144, 512, 4, 0.2f);

    // P = hfc @ Wih^T + (bih + bhh)
    k_gemm_mfma<<<dim3(32, 8, 1), 256, 0, stream>>>(hfc, wihb, part, 512, 2048, 512, 512);
    k_epilogue<<<1024, 256, 0, stream>>>(part, bias2, nullptr, P, 1048576, 2048, 1, 1.0f);

    // LSTM
    for (int t = 0; t < 16; ++t) {
        const short* hin = (t & 1) ? hm1 : hm0;
        short* hout      = (t & 1) ? hm0 : hm1;
        k_lstm2<<<32, 256, 0, stream>>>(P, whhb, done, hin, hout, cS, nh, hA, t);
    }

    // heads
    k_gemm_mfma<<<dim3(8, 8, 1), 256, 0, stream>>>(nh, a1b, part, 512, 512, 512, 512);
    k_epilogue<<<256, 256, 0, stream>>>(part, Ab1, aA, nullptr, 262144, 512, 1, 0.01f);
    k_gemm_mfma<<<dim3(8, 8, 1), 256, 0, stream>>>(nh, c1b, part, 512, 512, 512, 512);
    k_epilogue<<<256, 256, 0, stream>>>(part, Cb1, aC, nullptr, 262144, 512, 1, 0.01f);
    k_heads<<<1152, 256, 0, stream>>>(aA, aC, a2b, Ab2, c2b, Cb2, out);

    k_states_out<<<64, 256, 0, stream>>>(hA, cS, out + 4608, out + 20992);
}